// Round 1
// baseline (238.121 us; speedup 1.0000x reference)
//
#include <hip/hip_runtime.h>

// Problem constants (from reference): B=4, N=2048, M=4096, D=1, C=4, K=32
#define B_  4
#define N_  2048
#define M_  4096
#define C_  4
#define K_  32
#define CK_ 128          // C*K

// ---------------- Stage 1: zt partials ----------------
// zt[b,c,n,k] = sum_m exp(coef*(xz[m]-x[b,n])^2) * z[b,c,m,k],  coef = -0.5/exp(log_scale)
// Tile: NT=128 targets x CK=128 (c,k) columns per block; M split MS-ways across blocks,
// each split writes its own partial buffer (no atomics -> deterministic).
#define NT 128
#define MT 64

template <int MS>
__global__ __launch_bounds__(256) void zt_partial_kernel(
    const float* __restrict__ xz, const float* __restrict__ x,
    const float* __restrict__ z,  const float* __restrict__ ls,
    float* __restrict__ ztp)
{
    __shared__ __align__(16) float xz_s[MT];
    __shared__ __align__(16) float x_s[NT];
    __shared__ __align__(16) float w_s[MT][NT];
    __shared__ __align__(16) float z_s[MT][CK_];

    const int tid  = threadIdx.x;
    const int ms   = blockIdx.x;
    const int nblk = blockIdx.y * NT;
    const int b    = blockIdx.z;

    const float coef = -0.5f * __expf(-ls[0]);

    if (tid < NT) x_s[tid] = x[b * N_ + nblk + tid];

    float acc[8][8];
    #pragma unroll
    for (int i = 0; i < 8; ++i)
        #pragma unroll
        for (int j = 0; j < 8; ++j) acc[i][j] = 0.0f;

    const int n0  = (tid & 15) * 8;   // 16 groups x 8 = 128 targets
    const int ck0 = (tid >> 4) * 8;   // 16 groups x 8 = 128 (c,k) columns

    const int MCHUNK = M_ / MS;
    const int mstart = ms * MCHUNK;

    for (int mc = 0; mc < MCHUNK; mc += MT) {
        const int m0g = mstart + mc;
        __syncthreads();                         // previous-iter LDS reads done
        if (tid < MT) xz_s[tid] = xz[m0g + tid];
        __syncthreads();                         // xz_s visible
        // compute w tile: 64 m x 128 n
        for (int e = tid; e < MT * NT; e += 256) {
            const int mm = e >> 7;
            const int nn = e & (NT - 1);
            const float d = xz_s[mm] - x_s[nn];
            w_s[mm][nn] = __expf(coef * d * d);
        }
        // stage z tile: z[b][c][m0g+mm][k] -> z_s[mm][c*32+k]
        for (int e4 = tid; e4 < MT * CK_ / 4; e4 += 256) {
            const int mm  = e4 >> 5;
            const int ck4 = e4 & 31;
            const int c   = ck4 >> 3;
            const int k4  = ck4 & 7;
            const float4 v = *(const float4*)&z[((((size_t)b * C_ + c) * M_) + m0g + mm) * K_ + k4 * 4];
            *(float4*)&z_s[mm][ck4 * 4] = v;
        }
        __syncthreads();
        // inner product: acc[8 n][8 ck] over 64 m
        for (int mm = 0; mm < MT; ++mm) {
            const float4 a0 = *(const float4*)&w_s[mm][n0];
            const float4 a1 = *(const float4*)&w_s[mm][n0 + 4];
            const float4 b0 = *(const float4*)&z_s[mm][ck0];
            const float4 b1 = *(const float4*)&z_s[mm][ck0 + 4];
            const float av[8] = {a0.x, a0.y, a0.z, a0.w, a1.x, a1.y, a1.z, a1.w};
            const float bv[8] = {b0.x, b0.y, b0.z, b0.w, b1.x, b1.y, b1.z, b1.w};
            #pragma unroll
            for (int i = 0; i < 8; ++i)
                #pragma unroll
                for (int j = 0; j < 8; ++j)
                    acc[i][j] = fmaf(av[i], bv[j], acc[i][j]);
        }
    }

    // write this split's partial zt
    float* dst = ztp + (size_t)ms * (B_ * C_ * N_ * K_);
    #pragma unroll
    for (int i = 0; i < 8; ++i) {
        const int n = nblk + n0 + i;
        #pragma unroll
        for (int j4 = 0; j4 < 2; ++j4) {
            const int ck = ck0 + j4 * 4;
            const int c  = ck >> 5;
            const int k  = ck & 31;
            const float4 v = make_float4(acc[i][j4 * 4 + 0], acc[i][j4 * 4 + 1],
                                         acc[i][j4 * 4 + 2], acc[i][j4 * 4 + 3]);
            *(float4*)&dst[(((size_t)b * C_ + c) * N_ + n) * K_ + k] = v;
        }
    }
}

// ---------------- Stage 1b: reduce partials (in place into slot 0) ----------------
template <int MS>
__global__ __launch_bounds__(256) void zt_reduce_kernel(float* __restrict__ ztp)
{
    const size_t t4     = (size_t)blockIdx.x * 256 + threadIdx.x;  // float4 index
    const size_t stride = (size_t)(B_ * C_ * N_ * K_);             // floats per partial
    float4 s = *(const float4*)&ztp[t4 * 4];
    #pragma unroll
    for (int p = 1; p < MS; ++p) {
        const float4 v = *(const float4*)&ztp[(size_t)p * stride + t4 * 4];
        s.x += v.x; s.y += v.y; s.z += v.z; s.w += v.w;
    }
    *(float4*)&ztp[t4 * 4] = s;
}

// ---------------- Stage 2: out = zt @ zt^T per (b,c) ----------------
#define TB 128
__global__ __launch_bounds__(256) void out_kernel(
    const float* __restrict__ zt, float* __restrict__ out)
{
    __shared__ __align__(16) float za_s[K_][TB + 4];  // k-major, padded row (528B, 16B-mult)
    __shared__ __align__(16) float zb_s[K_][TB + 4];

    const int tid  = threadIdx.x;
    const int mblk = blockIdx.x * TB;
    const int nblk = blockIdx.y * TB;
    const int bc   = blockIdx.z;

    const float* base = zt + (size_t)bc * (N_ * K_);
    for (int e = tid; e < TB * K_; e += 256) {
        const int r = e >> 5;
        const int k = e & 31;
        za_s[k][r] = base[(size_t)(nblk + r) * K_ + k];
        zb_s[k][r] = base[(size_t)(mblk + r) * K_ + k];
    }
    __syncthreads();

    const int m0 = (tid & 15) * 8;   // contiguous m per thread -> coalesced f4 stores
    const int n0 = (tid >> 4) * 8;

    float acc[8][8];
    #pragma unroll
    for (int i = 0; i < 8; ++i)
        #pragma unroll
        for (int j = 0; j < 8; ++j) acc[i][j] = 0.0f;

    #pragma unroll 8
    for (int k = 0; k < K_; ++k) {
        const float4 a0 = *(const float4*)&za_s[k][n0];
        const float4 a1 = *(const float4*)&za_s[k][n0 + 4];
        const float4 b0 = *(const float4*)&zb_s[k][m0];
        const float4 b1 = *(const float4*)&zb_s[k][m0 + 4];
        const float av[8] = {a0.x, a0.y, a0.z, a0.w, a1.x, a1.y, a1.z, a1.w};
        const float bv[8] = {b0.x, b0.y, b0.z, b0.w, b1.x, b1.y, b1.z, b1.w};
        #pragma unroll
        for (int i = 0; i < 8; ++i)
            #pragma unroll
            for (int j = 0; j < 8; ++j)
                acc[i][j] = fmaf(av[i], bv[j], acc[i][j]);
    }

    float* ob = out + (size_t)bc * N_ * N_;
    #pragma unroll
    for (int i = 0; i < 8; ++i) {
        const size_t row = (size_t)(nblk + n0 + i) * N_ + mblk + m0;
        *(float4*)&ob[row]     = make_float4(acc[i][0], acc[i][1], acc[i][2], acc[i][3]);
        *(float4*)&ob[row + 4] = make_float4(acc[i][4], acc[i][5], acc[i][6], acc[i][7]);
    }
}

// ---------------- Stage 0: copy xz to output 0 ----------------
__global__ __launch_bounds__(256) void copy_xz_kernel(
    const float* __restrict__ xz, float* __restrict__ out)
{
    const int t = blockIdx.x * 256 + threadIdx.x;   // 1024 threads x float4 = 4096 floats
    *(float4*)&out[t * 4] = *(const float4*)&xz[t * 4];
}

extern "C" void kernel_launch(void* const* d_in, const int* in_sizes, int n_in,
                              void* d_out, int out_size, void* d_ws, size_t ws_size,
                              hipStream_t stream)
{
    const float* xz = (const float*)d_in[0];
    const float* x  = (const float*)d_in[1];
    const float* z  = (const float*)d_in[2];
    const float* ls = (const float*)d_in[3];
    float* out = (float*)d_out;
    float* ztp = (float*)d_ws;

    (void)in_sizes; (void)n_in; (void)out_size;

    // output 0: xz passthrough (M_*1 floats)
    copy_xz_kernel<<<dim3(M_ / 4 / 256), dim3(256), 0, stream>>>(xz, out);

    const size_t zt_floats = (size_t)B_ * C_ * N_ * K_;   // 1 Mi floats = 4 MiB
    if (ws_size >= (size_t)8 * zt_floats * sizeof(float)) {
        // 8-way M split: 512 blocks (2/CU), deterministic partials + reduce
        zt_partial_kernel<8><<<dim3(8, N_ / NT, B_), dim3(256), 0, stream>>>(xz, x, z, ls, ztp);
        zt_reduce_kernel<8><<<dim3((unsigned)(zt_floats / 4 / 256)), dim3(256), 0, stream>>>(ztp);
    } else {
        // fallback: no split (64 blocks, slower but correct in 4 MiB of ws)
        zt_partial_kernel<1><<<dim3(1, N_ / NT, B_), dim3(256), 0, stream>>>(xz, x, z, ls, ztp);
    }

    // output 1: out[b,c,n,m] at offset M_ (after xz)
    out_kernel<<<dim3(N_ / TB, N_ / TB, B_ * C_), dim3(256), 0, stream>>>(ztp, out + M_);
}

// Round 3
// 161.491 us; speedup vs baseline: 1.4745x; 1.4745x over previous
//
#include <hip/hip_runtime.h>
#include <hip/hip_bf16.h>

// Problem constants: B=4, N=2048, M=4096, D=1, C=4, K=32
#define B_  4
#define N_  2048
#define M_  4096
#define C_  4
#define K_  32
#define CK_ 128          // C*K

typedef float f32x4 __attribute__((ext_vector_type(4)));
typedef short s16x8 __attribute__((ext_vector_type(8)));

__device__ __forceinline__ short f2bf(float f) {
    union { __hip_bfloat16 h; short s; } u;
    u.h = __float2bfloat16(f);
    return u.s;
}

// ---------------- Stage 1 (MFMA): zt[b,c,n,k] = sum_m exp(coef*d^2) * z[b,c,m,k] ----------------
// Block: 256 thr = 4 waves (2x2 over n/ck), tile 128n x 128ck, K-loop over m.
// A-operand (w^T) generated in registers (8 exps/lane/frag); B-operand (z) staged
// ck-major bf16 in LDS (row stride 136 shorts = 16B-aligned, 2-way-free b128 reads).
#define MT1 128          // m per staging chunk
#define ZS  136          // padded shorts per z_s row

template <int MS>
__global__ __launch_bounds__(256) void zt_mfma_kernel(
    const float* __restrict__ xz, const float* __restrict__ x,
    const float* __restrict__ z,  const float* __restrict__ ls,
    float* __restrict__ ztp)
{
    constexpr int MCH = M_ / MS;
    __shared__ __align__(16) float xz_s[MCH];
    __shared__ __align__(16) short z_s[CK_][ZS];

    const int tid  = threadIdx.x;
    const int lane = tid & 63;
    const int wave = tid >> 6;
    const int wn   = wave >> 1;       // n 64-half
    const int wc   = wave & 1;        // ck 64-half
    const int ms   = blockIdx.x;
    const int nblk = blockIdx.y * 128;
    const int b    = blockIdx.z;
    const int l15  = lane & 15;
    const int lg   = lane >> 4;       // 0..3

    const float coef = -0.5f * __expf(-ls[0]);

    // per-lane x values: A-frag row n = nblk + wn*64 + fa*16 + (lane&15)
    float xv[4];
    #pragma unroll
    for (int fa = 0; fa < 4; ++fa)
        xv[fa] = x[b * N_ + nblk + wn * 64 + fa * 16 + l15];

    const int mstart = ms * MCH;
    for (int i = tid; i < MCH; i += 256) xz_s[i] = xz[mstart + i];

    f32x4 acc[4][4];
    #pragma unroll
    for (int i = 0; i < 4; ++i)
        #pragma unroll
        for (int j = 0; j < 4; ++j) acc[i][j] = (f32x4)0.0f;

    for (int mc = 0; mc < MCH; mc += MT1) {
        __syncthreads();                       // z_s reuse + xz_s ready (first iter)
        // stage z[b][*][m..m+127][*] -> z_s[ck][m] bf16; 4 m's packed per b64 write,
        // global reads k-fastest (coalesced 128B segments per c-group)
        #pragma unroll
        for (int it = 0; it < CK_ * (MT1 / 4) / 256; ++it) {   // 16 iters
            const int u  = tid + it * 256;
            const int ck = u & 127;
            const int mq = u >> 7;             // 0..31
            const int m  = mstart + mc + mq * 4;
            const float* zp = &z[(((size_t)b * C_ + (ck >> 5)) * M_ + m) * K_ + (ck & 31)];
            short4 pk;
            pk.x = f2bf(zp[0]);
            pk.y = f2bf(zp[K_]);
            pk.z = f2bf(zp[2 * K_]);
            pk.w = f2bf(zp[3 * K_]);
            *reinterpret_cast<short4*>(&z_s[ck][mq * 4]) = pk;
        }
        __syncthreads();
        #pragma unroll
        for (int ks = 0; ks < MT1 / 32; ++ks) {
            // this lane's 8 m-slots (same for all 4 A-frags): broadcast LDS reads
            const float* xzp = &xz_s[mc + ks * 32 + lg * 8];
            const f32x4 t0 = *reinterpret_cast<const f32x4*>(xzp);
            const f32x4 t1 = *reinterpret_cast<const f32x4*>(xzp + 4);
            const float t[8] = {t0.x, t0.y, t0.z, t0.w, t1.x, t1.y, t1.z, t1.w};
            s16x8 af[4];
            #pragma unroll
            for (int fa = 0; fa < 4; ++fa) {
                #pragma unroll
                for (int j = 0; j < 8; ++j) {
                    const float d = t[j] - xv[fa];
                    af[fa][j] = f2bf(__expf(coef * d * d));
                }
            }
            s16x8 bfg[4];
            #pragma unroll
            for (int fc = 0; fc < 4; ++fc)
                bfg[fc] = *reinterpret_cast<const s16x8*>(
                    &z_s[wc * 64 + fc * 16 + l15][ks * 32 + lg * 8]);
            #pragma unroll
            for (int fa = 0; fa < 4; ++fa)
                #pragma unroll
                for (int fc = 0; fc < 4; ++fc)
                    acc[fa][fc] = __builtin_amdgcn_mfma_f32_16x16x32_bf16(
                        af[fa], bfg[fc], acc[fa][fc], 0, 0, 0);
        }
    }

    // write this split's partial zt; D layout: col(=ck)=lane&15, row(=n)=(lane>>4)*4+r
    float* dst = ztp + (size_t)ms * (B_ * C_ * N_ * K_);
    #pragma unroll
    for (int fc = 0; fc < 4; ++fc) {
        const int ck = wc * 64 + fc * 16 + l15;
        const int c  = ck >> 5, k = ck & 31;
        #pragma unroll
        for (int fa = 0; fa < 4; ++fa) {
            const int n0 = nblk + wn * 64 + fa * 16 + lg * 4;
            #pragma unroll
            for (int r = 0; r < 4; ++r)
                dst[(((size_t)b * C_ + c) * N_ + n0 + r) * K_ + k] = acc[fa][fc][r];
        }
    }
}

// ---------------- Stage 1b: reduce partials (into slot 0) ----------------
template <int MS>
__global__ __launch_bounds__(256) void zt_reduce_kernel(float* __restrict__ ztp)
{
    const size_t t4     = (size_t)blockIdx.x * 256 + threadIdx.x;
    const size_t stride = (size_t)(B_ * C_ * N_ * K_);
    float4 s = *(const float4*)&ztp[t4 * 4];
    #pragma unroll
    for (int p = 1; p < MS; ++p) {
        const float4 v = *(const float4*)&ztp[(size_t)p * stride + t4 * 4];
        s.x += v.x; s.y += v.y; s.z += v.z; s.w += v.w;
    }
    *(float4*)&ztp[t4 * 4] = s;
}

// ---------------- Stage 2: out = zt @ zt^T per (b,c) ----------------
#define TB 128
__global__ __launch_bounds__(256) void out_kernel(
    const float* __restrict__ zt, float* __restrict__ out)
{
    __shared__ __align__(16) float za_s[K_][TB + 4];
    __shared__ __align__(16) float zb_s[K_][TB + 4];

    const int tid  = threadIdx.x;
    const int mblk = blockIdx.x * TB;
    const int nblk = blockIdx.y * TB;
    const int bc   = blockIdx.z;

    const float* base = zt + (size_t)bc * (N_ * K_);
    for (int e = tid; e < TB * K_; e += 256) {
        const int r = e >> 5;
        const int k = e & 31;
        za_s[k][r] = base[(size_t)(nblk + r) * K_ + k];
        zb_s[k][r] = base[(size_t)(mblk + r) * K_ + k];
    }
    __syncthreads();

    const int m0 = (tid & 15) * 8;
    const int n0 = (tid >> 4) * 8;

    float acc[8][8];
    #pragma unroll
    for (int i = 0; i < 8; ++i)
        #pragma unroll
        for (int j = 0; j < 8; ++j) acc[i][j] = 0.0f;

    #pragma unroll 8
    for (int k = 0; k < K_; ++k) {
        const float4 a0 = *(const float4*)&za_s[k][n0];
        const float4 a1 = *(const float4*)&za_s[k][n0 + 4];
        const float4 b0 = *(const float4*)&zb_s[k][m0];
        const float4 b1 = *(const float4*)&zb_s[k][m0 + 4];
        const float av[8] = {a0.x, a0.y, a0.z, a0.w, a1.x, a1.y, a1.z, a1.w};
        const float bv[8] = {b0.x, b0.y, b0.z, b0.w, b1.x, b1.y, b1.z, b1.w};
        #pragma unroll
        for (int i = 0; i < 8; ++i)
            #pragma unroll
            for (int j = 0; j < 8; ++j)
                acc[i][j] = fmaf(av[i], bv[j], acc[i][j]);
    }

    float* ob = out + (size_t)bc * N_ * N_;
    #pragma unroll
    for (int i = 0; i < 8; ++i) {
        const size_t row = (size_t)(nblk + n0 + i) * N_ + mblk + m0;
        const f32x4 v0 = {acc[i][0], acc[i][1], acc[i][2], acc[i][3]};
        const f32x4 v1 = {acc[i][4], acc[i][5], acc[i][6], acc[i][7]};
        __builtin_nontemporal_store(v0, (f32x4*)&ob[row]);
        __builtin_nontemporal_store(v1, (f32x4*)&ob[row + 4]);
    }
}

// ---------------- Stage 0: copy xz to output 0 ----------------
__global__ __launch_bounds__(256) void copy_xz_kernel(
    const float* __restrict__ xz, float* __restrict__ out)
{
    const int t = blockIdx.x * 256 + threadIdx.x;
    *(float4*)&out[t * 4] = *(const float4*)&xz[t * 4];
}

extern "C" void kernel_launch(void* const* d_in, const int* in_sizes, int n_in,
                              void* d_out, int out_size, void* d_ws, size_t ws_size,
                              hipStream_t stream)
{
    const float* xz = (const float*)d_in[0];
    const float* x  = (const float*)d_in[1];
    const float* z  = (const float*)d_in[2];
    const float* ls = (const float*)d_in[3];
    float* out = (float*)d_out;
    float* ztp = (float*)d_ws;

    (void)in_sizes; (void)n_in; (void)out_size;

    copy_xz_kernel<<<dim3(M_ / 4 / 256), dim3(256), 0, stream>>>(xz, out);

    const size_t zt_floats = (size_t)B_ * C_ * N_ * K_;   // 4 MiB
    if (ws_size >= (size_t)8 * zt_floats * sizeof(float)) {
        zt_mfma_kernel<8><<<dim3(8, N_ / 128, B_), dim3(256), 0, stream>>>(xz, x, z, ls, ztp);
        zt_reduce_kernel<8><<<dim3((unsigned)(zt_floats / 4 / 256)), dim3(256), 0, stream>>>(ztp);
    } else {
        zt_mfma_kernel<1><<<dim3(1, N_ / 128, B_), dim3(256), 0, stream>>>(xz, x, z, ls, ztp);
    }

    out_kernel<<<dim3(N_ / TB, N_ / TB, B_ * C_), dim3(256), 0, stream>>>(ztp, out + M_);
}

// Round 4
// 106.455 us; speedup vs baseline: 2.2368x; 1.5170x over previous
//
#include <hip/hip_runtime.h>
#include <hip/hip_bf16.h>

// Problem constants: B=4, N=2048, M=4096, D=1, C=4, K=32
#define B_  4
#define N_  2048
#define M_  4096
#define C_  4
#define K_  32
#define CK_ 128          // C*K

typedef float f32x4 __attribute__((ext_vector_type(4)));
typedef short s16x8 __attribute__((ext_vector_type(8)));

__device__ __forceinline__ short f2bf(float f) {
    union { __hip_bfloat16 h; short s; } u;
    u.h = __float2bfloat16(f);
    return u.s;
}

// ---------------- Stage 1 (MFMA): zt[b,c,n,k] = sum_m exp(coef*d^2) * z[b,c,m,k] ----------------
// Block: 256 thr = 4 waves (2x2 over n/ck), tile 128n x 128ck, K-loop over m.
// A-operand (w^T) generated in registers; B-operand (z) staged ck-major bf16 in LDS.
#define MT1 128          // m per staging chunk
#define ZS  136          // padded shorts per z_s row

template <int MS>
__global__ __launch_bounds__(256) void zt_mfma_kernel(
    const float* __restrict__ xz, const float* __restrict__ x,
    const float* __restrict__ z,  const float* __restrict__ ls,
    float* __restrict__ ztp)
{
    constexpr int MCH = M_ / MS;
    __shared__ __align__(16) float xz_s[MCH];
    __shared__ __align__(16) short z_s[CK_][ZS];

    const int tid  = threadIdx.x;
    const int lane = tid & 63;
    const int wave = tid >> 6;
    const int wn   = wave >> 1;       // n 64-half
    const int wc   = wave & 1;        // ck 64-half
    const int ms   = blockIdx.x;
    const int nblk = blockIdx.y * 128;
    const int b    = blockIdx.z;
    const int l15  = lane & 15;
    const int lg   = lane >> 4;       // 0..3

    const float coef = -0.5f * __expf(-ls[0]);

    float xv[4];
    #pragma unroll
    for (int fa = 0; fa < 4; ++fa)
        xv[fa] = x[b * N_ + nblk + wn * 64 + fa * 16 + l15];

    const int mstart = ms * MCH;
    for (int i = tid; i < MCH; i += 256) xz_s[i] = xz[mstart + i];

    f32x4 acc[4][4];
    #pragma unroll
    for (int i = 0; i < 4; ++i)
        #pragma unroll
        for (int j = 0; j < 4; ++j) acc[i][j] = (f32x4)0.0f;

    for (int mc = 0; mc < MCH; mc += MT1) {
        __syncthreads();
        #pragma unroll
        for (int it = 0; it < CK_ * (MT1 / 4) / 256; ++it) {   // 16 iters
            const int u  = tid + it * 256;
            const int ck = u & 127;
            const int mq = u >> 7;             // 0..31
            const int m  = mstart + mc + mq * 4;
            const float* zp = &z[(((size_t)b * C_ + (ck >> 5)) * M_ + m) * K_ + (ck & 31)];
            short4 pk;
            pk.x = f2bf(zp[0]);
            pk.y = f2bf(zp[K_]);
            pk.z = f2bf(zp[2 * K_]);
            pk.w = f2bf(zp[3 * K_]);
            *reinterpret_cast<short4*>(&z_s[ck][mq * 4]) = pk;
        }
        __syncthreads();
        #pragma unroll
        for (int ks = 0; ks < MT1 / 32; ++ks) {
            const float* xzp = &xz_s[mc + ks * 32 + lg * 8];
            const f32x4 t0 = *reinterpret_cast<const f32x4*>(xzp);
            const f32x4 t1 = *reinterpret_cast<const f32x4*>(xzp + 4);
            const float t[8] = {t0.x, t0.y, t0.z, t0.w, t1.x, t1.y, t1.z, t1.w};
            s16x8 af[4];
            #pragma unroll
            for (int fa = 0; fa < 4; ++fa) {
                #pragma unroll
                for (int j = 0; j < 8; ++j) {
                    const float d = t[j] - xv[fa];
                    af[fa][j] = f2bf(__expf(coef * d * d));
                }
            }
            s16x8 bfg[4];
            #pragma unroll
            for (int fc = 0; fc < 4; ++fc)
                bfg[fc] = *reinterpret_cast<const s16x8*>(
                    &z_s[wc * 64 + fc * 16 + l15][ks * 32 + lg * 8]);
            #pragma unroll
            for (int fa = 0; fa < 4; ++fa)
                #pragma unroll
                for (int fc = 0; fc < 4; ++fc)
                    acc[fa][fc] = __builtin_amdgcn_mfma_f32_16x16x32_bf16(
                        af[fa], bfg[fc], acc[fa][fc], 0, 0, 0);
        }
    }

    // write this split's partial zt; D layout: col(=ck)=lane&15, row(=n)=(lane>>4)*4+r
    float* dst = ztp + (size_t)ms * (B_ * C_ * N_ * K_);
    #pragma unroll
    for (int fc = 0; fc < 4; ++fc) {
        const int ck = wc * 64 + fc * 16 + l15;
        const int c  = ck >> 5, k = ck & 31;
        #pragma unroll
        for (int fa = 0; fa < 4; ++fa) {
            const int n0 = nblk + wn * 64 + fa * 16 + lg * 4;
            #pragma unroll
            for (int r = 0; r < 4; ++r)
                dst[(((size_t)b * C_ + c) * N_ + n0 + r) * K_ + k] = acc[fa][fc][r];
        }
    }
}

// ---------------- Stage 1b: reduce MS partials -> bf16 zt ----------------
template <int MS>
__global__ __launch_bounds__(256) void zt_reduce_bf16_kernel(
    const float* __restrict__ ztp, unsigned short* __restrict__ ztb)
{
    const size_t t      = (size_t)blockIdx.x * 256 + threadIdx.x;  // float4 index
    const size_t stride = (size_t)(B_ * C_ * N_ * K_);
    f32x4 s = *(const f32x4*)&ztp[t * 4];
    #pragma unroll
    for (int p = 1; p < MS; ++p) {
        const f32x4 v = *(const f32x4*)&ztp[(size_t)p * stride + t * 4];
        s += v;
    }
    short4 pk;
    pk.x = f2bf(s.x); pk.y = f2bf(s.y); pk.z = f2bf(s.z); pk.w = f2bf(s.w);
    *reinterpret_cast<short4*>(&ztb[t * 4]) = pk;
}

// ---------------- Stage 2 (MFMA): out = zt @ zt^T per (b,c) ----------------
// 128x128 out tile, 4 waves (2x2), one 16x16x32 MFMA per frag pair (K=32 in one shot).
// Frags loaded straight from global (L2-resident, fully coalesced 1KB/instr).
// Epilogue: acc -> padded LDS tile -> coalesced nontemporal float4 stores.
#define TB 128
__global__ __launch_bounds__(256) void out_mfma_kernel(
    const unsigned short* __restrict__ ztb, float* __restrict__ out)
{
    __shared__ __align__(16) float t_s[TB][132];

    const int tid  = threadIdx.x;
    const int lane = tid & 63;
    const int wave = tid >> 6;
    const int wn   = wave >> 1;       // n 64-half
    const int wm   = wave & 1;        // m 64-half
    const int l15  = lane & 15;
    const int lg   = lane >> 4;
    const int mblk = blockIdx.x * TB;
    const int nblk = blockIdx.y * TB;
    const int bc   = blockIdx.z;

    const unsigned short* base = ztb + (size_t)bc * (N_ * K_);

    s16x8 afr[4], bfr[4];
    #pragma unroll
    for (int f = 0; f < 4; ++f) {
        const int n = nblk + wn * 64 + f * 16 + l15;
        afr[f] = *reinterpret_cast<const s16x8*>(&base[(size_t)n * K_ + lg * 8]);
        const int m = mblk + wm * 64 + f * 16 + l15;
        bfr[f] = *reinterpret_cast<const s16x8*>(&base[(size_t)m * K_ + lg * 8]);
    }

    f32x4 acc[4][4];
    #pragma unroll
    for (int i = 0; i < 4; ++i)
        #pragma unroll
        for (int j = 0; j < 4; ++j) acc[i][j] = (f32x4)0.0f;

    #pragma unroll
    for (int fa = 0; fa < 4; ++fa)
        #pragma unroll
        for (int fm = 0; fm < 4; ++fm)
            acc[fa][fm] = __builtin_amdgcn_mfma_f32_16x16x32_bf16(
                afr[fa], bfr[fm], acc[fa][fm], 0, 0, 0);

    // scatter acc into LDS: D col = m (lane&15), row = n ((lane>>4)*4 + r)
    #pragma unroll
    for (int fa = 0; fa < 4; ++fa) {
        const int nrow = wn * 64 + fa * 16 + lg * 4;
        #pragma unroll
        for (int fm = 0; fm < 4; ++fm) {
            const int mcol = wm * 64 + fm * 16 + l15;
            #pragma unroll
            for (int r = 0; r < 4; ++r)
                t_s[nrow + r][mcol] = acc[fa][fm][r];
        }
    }
    __syncthreads();

    float* ob = out + (size_t)bc * N_ * N_;
    #pragma unroll
    for (int it = 0; it < TB * TB / 4 / 256; ++it) {   // 16 iters
        const int e   = tid + it * 256;
        const int row = e >> 5;            // 32 float4 per row
        const int c4  = e & 31;
        const f32x4 v = *reinterpret_cast<const f32x4*>(&t_s[row][c4 * 4]);
        __builtin_nontemporal_store(v, (f32x4*)&ob[(size_t)(nblk + row) * N_ + mblk + c4 * 4]);
    }
}

// ---------------- Stage 0: copy xz to output 0 ----------------
__global__ __launch_bounds__(256) void copy_xz_kernel(
    const float* __restrict__ xz, float* __restrict__ out)
{
    const int t = blockIdx.x * 256 + threadIdx.x;
    *(float4*)&out[t * 4] = *(const float4*)&xz[t * 4];
}

extern "C" void kernel_launch(void* const* d_in, const int* in_sizes, int n_in,
                              void* d_out, int out_size, void* d_ws, size_t ws_size,
                              hipStream_t stream)
{
    const float* xz = (const float*)d_in[0];
    const float* x  = (const float*)d_in[1];
    const float* z  = (const float*)d_in[2];
    const float* ls = (const float*)d_in[3];
    float* out = (float*)d_out;

    (void)in_sizes; (void)n_in; (void)out_size;

    const size_t ztf = (size_t)B_ * C_ * N_ * K_;            // 1 Mi elements
    unsigned short* ztb = (unsigned short*)d_ws;             // bf16 zt: 2 MiB
    float* ztp = (float*)((char*)d_ws + ztf * sizeof(unsigned short));

    copy_xz_kernel<<<dim3(M_ / 4 / 256), dim3(256), 0, stream>>>(xz, out);

    const size_t need16 = ztf * 2 + (size_t)16 * ztf * 4;
    const size_t need8  = ztf * 2 + (size_t)8  * ztf * 4;
    if (ws_size >= need16) {
        zt_mfma_kernel<16><<<dim3(16, N_ / 128, B_), dim3(256), 0, stream>>>(xz, x, z, ls, ztp);
        zt_reduce_bf16_kernel<16><<<dim3((unsigned)(ztf / 4 / 256)), dim3(256), 0, stream>>>(ztp, ztb);
    } else if (ws_size >= need8) {
        zt_mfma_kernel<8><<<dim3(8, N_ / 128, B_), dim3(256), 0, stream>>>(xz, x, z, ls, ztp);
        zt_reduce_bf16_kernel<8><<<dim3((unsigned)(ztf / 4 / 256)), dim3(256), 0, stream>>>(ztp, ztb);
    } else {
        zt_mfma_kernel<4><<<dim3(4, N_ / 128, B_), dim3(256), 0, stream>>>(xz, x, z, ls, ztp);
        zt_reduce_bf16_kernel<4><<<dim3((unsigned)(ztf / 4 / 256)), dim3(256), 0, stream>>>(ztp, ztb);
    }

    out_mfma_kernel<<<dim3(N_ / TB, N_ / TB, B_ * C_), dim3(256), 0, stream>>>(ztb, out + M_);
}

// Round 5
// 85.545 us; speedup vs baseline: 2.7836x; 1.2444x over previous
//
#include <hip/hip_runtime.h>
#include <hip/hip_bf16.h>

// Problem constants: B=4, N=2048, M=4096, D=1, C=4, K=32
#define B_  4
#define N_  2048
#define M_  4096
#define C_  4
#define K_  32
#define CK_ 128          // C*K

typedef float f32x4 __attribute__((ext_vector_type(4)));
typedef short s16x8 __attribute__((ext_vector_type(8)));

__device__ __forceinline__ short f2bf(float f) {
    union { __hip_bfloat16 h; short s; } u;
    u.h = __float2bfloat16(f);
    return u.s;
}
__device__ __forceinline__ float bf2f(unsigned short u) {
    return __uint_as_float((unsigned)u << 16);
}

// ---------------- Stage 1 (MFMA): zt[b,c,n,k] = sum_m exp(coef*d^2) * z[b,c,m,k] ----------------
// Block: 256 thr = 4 waves (2x2 over n/ck), tile 128n x 128ck, K-loop over m.
// A-operand (w^T) generated in registers; B-operand (z) staged ck-major bf16 in LDS.
// Partials stored bf16 (halves partial traffic vs fp32).
#define MT1 128          // m per staging chunk
#define ZS  136          // padded shorts per z_s row

template <int MS>
__global__ __launch_bounds__(256, 4) void zt_mfma_kernel(
    const float* __restrict__ xz, const float* __restrict__ x,
    const float* __restrict__ z,  const float* __restrict__ ls,
    unsigned short* __restrict__ ztp)
{
    constexpr int MCH = M_ / MS;
    __shared__ __align__(16) float xz_s[MCH];
    __shared__ __align__(16) short z_s[CK_][ZS];

    const int tid  = threadIdx.x;
    const int lane = tid & 63;
    const int wave = tid >> 6;
    const int wn   = wave >> 1;       // n 64-half
    const int wc   = wave & 1;        // ck 64-half
    const int ms   = blockIdx.x;
    const int nblk = blockIdx.y * 128;
    const int b    = blockIdx.z;
    const int l15  = lane & 15;
    const int lg   = lane >> 4;       // 0..3

    const float coef = -0.5f * __expf(-ls[0]);

    float xv[4];
    #pragma unroll
    for (int fa = 0; fa < 4; ++fa)
        xv[fa] = x[b * N_ + nblk + wn * 64 + fa * 16 + l15];

    const int mstart = ms * MCH;
    for (int i = tid; i < MCH; i += 256) xz_s[i] = xz[mstart + i];

    f32x4 acc[4][4];
    #pragma unroll
    for (int i = 0; i < 4; ++i)
        #pragma unroll
        for (int j = 0; j < 4; ++j) acc[i][j] = (f32x4)0.0f;

    for (int mc = 0; mc < MCH; mc += MT1) {
        __syncthreads();
        #pragma unroll
        for (int it = 0; it < CK_ * (MT1 / 4) / 256; ++it) {   // 16 iters
            const int u  = tid + it * 256;
            const int ck = u & 127;
            const int mq = u >> 7;             // 0..31
            const int m  = mstart + mc + mq * 4;
            const float* zp = &z[(((size_t)b * C_ + (ck >> 5)) * M_ + m) * K_ + (ck & 31)];
            short4 pk;
            pk.x = f2bf(zp[0]);
            pk.y = f2bf(zp[K_]);
            pk.z = f2bf(zp[2 * K_]);
            pk.w = f2bf(zp[3 * K_]);
            *reinterpret_cast<short4*>(&z_s[ck][mq * 4]) = pk;
        }
        __syncthreads();
        #pragma unroll
        for (int ks = 0; ks < MT1 / 32; ++ks) {
            const float* xzp = &xz_s[mc + ks * 32 + lg * 8];
            const f32x4 t0 = *reinterpret_cast<const f32x4*>(xzp);
            const f32x4 t1 = *reinterpret_cast<const f32x4*>(xzp + 4);
            const float t[8] = {t0.x, t0.y, t0.z, t0.w, t1.x, t1.y, t1.z, t1.w};
            s16x8 af[4];
            #pragma unroll
            for (int fa = 0; fa < 4; ++fa) {
                #pragma unroll
                for (int j = 0; j < 8; ++j) {
                    const float d = t[j] - xv[fa];
                    af[fa][j] = f2bf(__expf(coef * d * d));
                }
            }
            s16x8 bfg[4];
            #pragma unroll
            for (int fc = 0; fc < 4; ++fc)
                bfg[fc] = *reinterpret_cast<const s16x8*>(
                    &z_s[wc * 64 + fc * 16 + l15][ks * 32 + lg * 8]);
            #pragma unroll
            for (int fa = 0; fa < 4; ++fa)
                #pragma unroll
                for (int fc = 0; fc < 4; ++fc)
                    acc[fa][fc] = __builtin_amdgcn_mfma_f32_16x16x32_bf16(
                        af[fa], bfg[fc], acc[fa][fc], 0, 0, 0);
        }
    }

    // write this split's bf16 partial zt; D layout: col(=ck)=lane&15, row(=n)=(lane>>4)*4+r
    unsigned short* dst = ztp + (size_t)ms * (B_ * C_ * N_ * K_);
    #pragma unroll
    for (int fc = 0; fc < 4; ++fc) {
        const int ck = wc * 64 + fc * 16 + l15;
        const int c  = ck >> 5, k = ck & 31;
        #pragma unroll
        for (int fa = 0; fa < 4; ++fa) {
            const int n0 = nblk + wn * 64 + fa * 16 + lg * 4;
            #pragma unroll
            for (int r = 0; r < 4; ++r)
                dst[(((size_t)b * C_ + c) * N_ + n0 + r) * K_ + k] =
                    (unsigned short)f2bf(acc[fa][fc][r]);
        }
    }
}

// ---------------- Stage 1b: reduce MS bf16 partials -> bf16 zt, + xz copy ----------------
template <int MS>
__global__ __launch_bounds__(256) void zt_reduce_copy_kernel(
    const unsigned short* __restrict__ ztp, unsigned short* __restrict__ ztb,
    const float* __restrict__ xz, float* __restrict__ out)
{
    if (blockIdx.x >= 1024) {   // 4 tail blocks: copy xz (4096 floats)
        const int t = (blockIdx.x - 1024) * 256 + threadIdx.x;
        *(float4*)&out[t * 4] = *(const float4*)&xz[t * 4];
        return;
    }
    const size_t t      = (size_t)blockIdx.x * 256 + threadIdx.x;  // 4-elem index
    const size_t stride = (size_t)(B_ * C_ * N_ * K_);
    float s0 = 0.f, s1 = 0.f, s2 = 0.f, s3 = 0.f;
    #pragma unroll
    for (int p = 0; p < MS; ++p) {
        const ushort4 v = *(const ushort4*)&ztp[(size_t)p * stride + t * 4];
        s0 += bf2f(v.x); s1 += bf2f(v.y); s2 += bf2f(v.z); s3 += bf2f(v.w);
    }
    ushort4 pk;
    pk.x = (unsigned short)f2bf(s0); pk.y = (unsigned short)f2bf(s1);
    pk.z = (unsigned short)f2bf(s2); pk.w = (unsigned short)f2bf(s3);
    *(ushort4*)&ztb[t * 4] = pk;
}

// ---------------- Stage 2 (MFMA): out = zt @ zt^T per (b,c) ----------------
// 128x128 out tile, 4 waves (2x2), one 16x16x32 MFMA per frag pair (K=32 in one shot).
// Frags loaded straight from global (L2-resident, fully coalesced 1KB/wave-instr).
// Epilogue: two 64-row passes through a 33.8KB LDS tile -> 4 blocks/CU.
#define TB 128
__global__ __launch_bounds__(256, 4) void out_mfma_kernel(
    const unsigned short* __restrict__ ztb, float* __restrict__ out)
{
    __shared__ __align__(16) float t_s[64][132];

    const int tid  = threadIdx.x;
    const int lane = tid & 63;
    const int wave = tid >> 6;
    const int wn   = wave >> 1;       // n 64-half
    const int wm   = wave & 1;        // m 64-half
    const int l15  = lane & 15;
    const int lg   = lane >> 4;
    const int mblk = blockIdx.x * TB;
    const int nblk = blockIdx.y * TB;
    const int bc   = blockIdx.z;

    const unsigned short* base = ztb + (size_t)bc * (N_ * K_);

    s16x8 afr[4], bfr[4];
    #pragma unroll
    for (int f = 0; f < 4; ++f) {
        const int n = nblk + wn * 64 + f * 16 + l15;
        afr[f] = *reinterpret_cast<const s16x8*>(&base[(size_t)n * K_ + lg * 8]);
        const int m = mblk + wm * 64 + f * 16 + l15;
        bfr[f] = *reinterpret_cast<const s16x8*>(&base[(size_t)m * K_ + lg * 8]);
    }

    f32x4 acc[4][4];
    #pragma unroll
    for (int i = 0; i < 4; ++i)
        #pragma unroll
        for (int j = 0; j < 4; ++j) acc[i][j] = (f32x4)0.0f;

    #pragma unroll
    for (int fa = 0; fa < 4; ++fa)
        #pragma unroll
        for (int fm = 0; fm < 4; ++fm)
            acc[fa][fm] = __builtin_amdgcn_mfma_f32_16x16x32_bf16(
                afr[fa], bfr[fm], acc[fa][fm], 0, 0, 0);

    float* ob = out + (size_t)bc * N_ * N_;

    // two passes over n-halves: waves with wn==p scatter their 64 rows, all store
    #pragma unroll
    for (int p = 0; p < 2; ++p) {
        if (p) __syncthreads();           // protect t_s from pass-0 readers
        if (wn == p) {
            #pragma unroll
            for (int fa = 0; fa < 4; ++fa) {
                const int row0 = fa * 16 + lg * 4;
                #pragma unroll
                for (int fm = 0; fm < 4; ++fm) {
                    const int mcol = wm * 64 + fm * 16 + l15;
                    #pragma unroll
                    for (int r = 0; r < 4; ++r)
                        t_s[row0 + r][mcol] = acc[fa][fm][r];
                }
            }
        }
        __syncthreads();
        #pragma unroll
        for (int it = 0; it < 8; ++it) {
            const int e   = tid + it * 256;
            const int row = e >> 5;
            const int c4  = e & 31;
            const f32x4 v = *reinterpret_cast<const f32x4*>(&t_s[row][c4 * 4]);
            __builtin_nontemporal_store(
                v, (f32x4*)&ob[(size_t)(nblk + p * 64 + row) * N_ + mblk + c4 * 4]);
        }
    }
}

extern "C" void kernel_launch(void* const* d_in, const int* in_sizes, int n_in,
                              void* d_out, int out_size, void* d_ws, size_t ws_size,
                              hipStream_t stream)
{
    const float* xz = (const float*)d_in[0];
    const float* x  = (const float*)d_in[1];
    const float* z  = (const float*)d_in[2];
    const float* ls = (const float*)d_in[3];
    float* out = (float*)d_out;

    (void)in_sizes; (void)n_in; (void)out_size;

    const size_t ztf = (size_t)B_ * C_ * N_ * K_;            // 1 Mi elements
    unsigned short* ztb = (unsigned short*)d_ws;             // final bf16 zt: 2 MiB
    unsigned short* ztp = ztb + ztf;                         // bf16 partials

    const size_t need16 = ztf * 2 + (size_t)16 * ztf * 2;
    const size_t need8  = ztf * 2 + (size_t)8  * ztf * 2;
    if (ws_size >= need16) {
        zt_mfma_kernel<16><<<dim3(16, N_ / 128, B_), dim3(256), 0, stream>>>(xz, x, z, ls, ztp);
        zt_reduce_copy_kernel<16><<<dim3(1028), dim3(256), 0, stream>>>(ztp, ztb, xz, out);
    } else if (ws_size >= need8) {
        zt_mfma_kernel<8><<<dim3(8, N_ / 128, B_), dim3(256), 0, stream>>>(xz, x, z, ls, ztp);
        zt_reduce_copy_kernel<8><<<dim3(1028), dim3(256), 0, stream>>>(ztp, ztb, xz, out);
    } else {
        zt_mfma_kernel<4><<<dim3(4, N_ / 128, B_), dim3(256), 0, stream>>>(xz, x, z, ls, ztp);
        zt_reduce_copy_kernel<4><<<dim3(1028), dim3(256), 0, stream>>>(ztp, ztb, xz, out);
    }

    out_mfma_kernel<<<dim3(N_ / TB, N_ / TB, B_ * C_), dim3(256), 0, stream>>>(ztb, out + M_);
}

// Round 6
// 82.156 us; speedup vs baseline: 2.8984x; 1.0413x over previous
//
#include <hip/hip_runtime.h>
#include <hip/hip_bf16.h>

// Problem constants: B=4, N=2048, M=4096, D=1, C=4, K=32
#define B_  4
#define N_  2048
#define M_  4096
#define C_  4
#define K_  32
#define CK_ 128          // C*K

typedef float f32x4 __attribute__((ext_vector_type(4)));
typedef short s16x8 __attribute__((ext_vector_type(8)));

__device__ __forceinline__ short f2bf(float f) {
    union { __hip_bfloat16 h; short s; } u;
    u.h = __float2bfloat16(f);
    return u.s;
}
__device__ __forceinline__ float bf2f(unsigned short u) {
    return __uint_as_float((unsigned)u << 16);
}

// ---------------- Stage 0a: transpose z -> zbt[(b*128+ck)][m] bf16 ----------------
// Read 8.4 MB coalesced, write 4.2 MB coalesced (via LDS tile). ~2 us.
__global__ __launch_bounds__(256) void z2bft_kernel(
    const float* __restrict__ z, unsigned short* __restrict__ zbt)
{
    __shared__ float t_f[K_][136];
    const int tid = threadIdx.x;
    const int m0  = blockIdx.x * 128;
    const int bc  = blockIdx.y;          // b*C + c

    #pragma unroll
    for (int it = 0; it < 4; ++it) {     // 128 m x 8 k4 = 1024 / 256
        const int e = tid + it * 256;
        const int m = e >> 3, k4 = e & 7;
        const f32x4 v = *(const f32x4*)&z[((size_t)bc * M_ + m0 + m) * K_ + k4 * 4];
        #pragma unroll
        for (int j = 0; j < 4; ++j) t_f[k4 * 4 + j][m] = v[j];
    }
    __syncthreads();
    #pragma unroll
    for (int it = 0; it < 2; ++it) {     // 32 k x 16 mq = 512 / 256
        const int e = tid + it * 256;
        const int r = e >> 4, mq = e & 15;
        s16x8 pk;
        #pragma unroll
        for (int j = 0; j < 8; ++j) pk[j] = f2bf(t_f[r][mq * 8 + j]);
        *(s16x8*)&zbt[((size_t)(bc * K_ + r)) * M_ + m0 + mq * 8] = pk;
    }
}

// ---------------- Stage 1 (MFMA): zt partials ----------------
// 512 thr = 8 waves (4 n-quadrants x 2 ck-halves), tile 128n x 128ck.
// z staged from pre-transposed bf16 zbt via b128 loads; double-buffered LDS,
// one barrier per chunk, loads for t+1 issued before compute of t.
#define ZS 136           // padded shorts per z_s row

template <int MS>
__global__ __launch_bounds__(512, 4) void zt_mfma_kernel(
    const float* __restrict__ xz, const float* __restrict__ x,
    const unsigned short* __restrict__ zbt, const float* __restrict__ ls,
    unsigned short* __restrict__ ztp)
{
    constexpr int MCH = M_ / MS;         // 512 for MS=8
    constexpr int NCH = MCH / 128;       // chunks of 128 m
    __shared__ __align__(16) float xz_s[MCH];
    __shared__ __align__(16) short z_s[2][CK_][ZS];

    const int tid  = threadIdx.x;
    const int lane = tid & 63;
    const int w    = tid >> 6;
    const int wq   = w >> 1;             // n quadrant 0..3 (32 rows each)
    const int wc   = w & 1;              // ck half
    const int l15  = lane & 15;
    const int lg   = lane >> 4;
    const int ms   = blockIdx.x;
    const int nblk = blockIdx.y * 128;
    const int b    = blockIdx.z;

    const float coef = -0.5f * __expf(-ls[0]);

    float xv[2];
    #pragma unroll
    for (int fa = 0; fa < 2; ++fa)
        xv[fa] = x[b * N_ + nblk + wq * 32 + fa * 16 + l15];

    const int mstart = ms * MCH;
    for (int i = tid; i < MCH; i += 512) xz_s[i] = xz[mstart + i];

    f32x4 acc[2][4];
    #pragma unroll
    for (int i = 0; i < 2; ++i)
        #pragma unroll
        for (int j = 0; j < 4; ++j) acc[i][j] = (f32x4)0.0f;

    s16x8 stg[4];
    // chunk staging: 128 ck x 16 mq(8m) = 2048 b128 units / 512 thr = 4 iters
    #define LOADC(t) { _Pragma("unroll")                                          \
        for (int it = 0; it < 4; ++it) {                                          \
            const int u = tid + it * 512;                                         \
            const int ck = u >> 4, mq = u & 15;                                   \
            stg[it] = *(const s16x8*)&zbt[((size_t)(b * CK_ + ck)) * M_ +         \
                                          mstart + (t) * 128 + mq * 8];           \
        } }
    #define WRITEC(t) { _Pragma("unroll")                                         \
        for (int it = 0; it < 4; ++it) {                                          \
            const int u = tid + it * 512;                                         \
            const int ck = u >> 4, mq = u & 15;                                   \
            *(s16x8*)&z_s[(t) & 1][ck][mq * 8] = stg[it];                         \
        } }

    LOADC(0); WRITEC(0);
    __syncthreads();

    for (int t = 0; t < NCH; ++t) {
        if (t + 1 < NCH) LOADC(t + 1);
        #pragma unroll
        for (int ks = 0; ks < 4; ++ks) {
            const float* xzp = &xz_s[t * 128 + ks * 32 + lg * 8];
            const f32x4 t0 = *reinterpret_cast<const f32x4*>(xzp);
            const f32x4 t1 = *reinterpret_cast<const f32x4*>(xzp + 4);
            const float tt[8] = {t0.x, t0.y, t0.z, t0.w, t1.x, t1.y, t1.z, t1.w};
            s16x8 af[2];
            #pragma unroll
            for (int fa = 0; fa < 2; ++fa) {
                #pragma unroll
                for (int j = 0; j < 8; ++j) {
                    const float d = tt[j] - xv[fa];
                    af[fa][j] = f2bf(__expf(coef * d * d));
                }
            }
            s16x8 bfg[4];
            #pragma unroll
            for (int fc = 0; fc < 4; ++fc)
                bfg[fc] = *reinterpret_cast<const s16x8*>(
                    &z_s[t & 1][wc * 64 + fc * 16 + l15][ks * 32 + lg * 8]);
            #pragma unroll
            for (int fa = 0; fa < 2; ++fa)
                #pragma unroll
                for (int fc = 0; fc < 4; ++fc)
                    acc[fa][fc] = __builtin_amdgcn_mfma_f32_16x16x32_bf16(
                        af[fa], bfg[fc], acc[fa][fc], 0, 0, 0);
        }
        if (t + 1 < NCH) WRITEC(t + 1);
        __syncthreads();
    }

    // bf16 partial write; D layout: col(=ck)=lane&15, row(=n)=(lane>>4)*4+r
    unsigned short* dst = ztp + (size_t)ms * (B_ * C_ * N_ * K_);
    #pragma unroll
    for (int fc = 0; fc < 4; ++fc) {
        const int ck = wc * 64 + fc * 16 + l15;
        const int c  = ck >> 5, k = ck & 31;
        #pragma unroll
        for (int fa = 0; fa < 2; ++fa) {
            const int n0 = nblk + wq * 32 + fa * 16 + lg * 4;
            #pragma unroll
            for (int r = 0; r < 4; ++r)
                dst[(((size_t)b * C_ + c) * N_ + n0 + r) * K_ + k] =
                    (unsigned short)f2bf(acc[fa][fc][r]);
        }
    }
    #undef LOADC
    #undef WRITEC
}

// ---------------- Stage 1b: reduce MS bf16 partials -> bf16 zt, + xz copy ----------------
template <int MS>
__global__ __launch_bounds__(256) void zt_reduce_copy_kernel(
    const unsigned short* __restrict__ ztp, unsigned short* __restrict__ ztb,
    const float* __restrict__ xz, float* __restrict__ out)
{
    if (blockIdx.x >= 1024) {   // 4 tail blocks: copy xz (4096 floats)
        const int t = (blockIdx.x - 1024) * 256 + threadIdx.x;
        *(float4*)&out[t * 4] = *(const float4*)&xz[t * 4];
        return;
    }
    const size_t t      = (size_t)blockIdx.x * 256 + threadIdx.x;
    const size_t stride = (size_t)(B_ * C_ * N_ * K_);
    float s0 = 0.f, s1 = 0.f, s2 = 0.f, s3 = 0.f;
    #pragma unroll
    for (int p = 0; p < MS; ++p) {
        const ushort4 v = *(const ushort4*)&ztp[(size_t)p * stride + t * 4];
        s0 += bf2f(v.x); s1 += bf2f(v.y); s2 += bf2f(v.z); s3 += bf2f(v.w);
    }
    ushort4 pk;
    pk.x = (unsigned short)f2bf(s0); pk.y = (unsigned short)f2bf(s1);
    pk.z = (unsigned short)f2bf(s2); pk.w = (unsigned short)f2bf(s3);
    *(ushort4*)&ztb[t * 4] = pk;
}

// ---------------- Stage 2 (MFMA): out = zt @ zt^T per (b,c) ----------------
#define TB 128
__global__ __launch_bounds__(256, 4) void out_mfma_kernel(
    const unsigned short* __restrict__ ztb, float* __restrict__ out)
{
    __shared__ __align__(16) float t_s[64][132];

    const int tid  = threadIdx.x;
    const int lane = tid & 63;
    const int wave = tid >> 6;
    const int wn   = wave >> 1;
    const int wm   = wave & 1;
    const int l15  = lane & 15;
    const int lg   = lane >> 4;
    const int mblk = blockIdx.x * TB;
    const int nblk = blockIdx.y * TB;
    const int bc   = blockIdx.z;

    const unsigned short* base = ztb + (size_t)bc * (N_ * K_);

    s16x8 afr[4], bfr[4];
    #pragma unroll
    for (int f = 0; f < 4; ++f) {
        const int n = nblk + wn * 64 + f * 16 + l15;
        afr[f] = *reinterpret_cast<const s16x8*>(&base[(size_t)n * K_ + lg * 8]);
        const int m = mblk + wm * 64 + f * 16 + l15;
        bfr[f] = *reinterpret_cast<const s16x8*>(&base[(size_t)m * K_ + lg * 8]);
    }

    f32x4 acc[4][4];
    #pragma unroll
    for (int i = 0; i < 4; ++i)
        #pragma unroll
        for (int j = 0; j < 4; ++j) acc[i][j] = (f32x4)0.0f;

    #pragma unroll
    for (int fa = 0; fa < 4; ++fa)
        #pragma unroll
        for (int fm = 0; fm < 4; ++fm)
            acc[fa][fm] = __builtin_amdgcn_mfma_f32_16x16x32_bf16(
                afr[fa], bfr[fm], acc[fa][fm], 0, 0, 0);

    float* ob = out + (size_t)bc * N_ * N_;

    #pragma unroll
    for (int p = 0; p < 2; ++p) {
        if (p) __syncthreads();
        if (wn == p) {
            #pragma unroll
            for (int fa = 0; fa < 4; ++fa) {
                const int row0 = fa * 16 + lg * 4;
                #pragma unroll
                for (int fm = 0; fm < 4; ++fm) {
                    const int mcol = wm * 64 + fm * 16 + l15;
                    #pragma unroll
                    for (int r = 0; r < 4; ++r)
                        t_s[row0 + r][mcol] = acc[fa][fm][r];
                }
            }
        }
        __syncthreads();
        #pragma unroll
        for (int it = 0; it < 8; ++it) {
            const int e   = tid + it * 256;
            const int row = e >> 5;
            const int c4  = e & 31;
            const f32x4 v = *reinterpret_cast<const f32x4*>(&t_s[row][c4 * 4]);
            __builtin_nontemporal_store(
                v, (f32x4*)&ob[(size_t)(nblk + p * 64 + row) * N_ + mblk + c4 * 4]);
        }
    }
}

extern "C" void kernel_launch(void* const* d_in, const int* in_sizes, int n_in,
                              void* d_out, int out_size, void* d_ws, size_t ws_size,
                              hipStream_t stream)
{
    const float* xz = (const float*)d_in[0];
    const float* x  = (const float*)d_in[1];
    const float* z  = (const float*)d_in[2];
    const float* ls = (const float*)d_in[3];
    float* out = (float*)d_out;

    (void)in_sizes; (void)n_in; (void)out_size;

    const size_t ztf = (size_t)B_ * C_ * N_ * K_;            // 1 Mi elements
    unsigned short* ztb = (unsigned short*)d_ws;             // final bf16 zt: 2 MiB
    unsigned short* zbt = ztb + ztf;                         // transposed bf16 z: 4 MiB
    unsigned short* ztp = zbt + (size_t)B_ * CK_ * M_;       // bf16 partials

    // transpose z -> zbt
    z2bft_kernel<<<dim3(M_ / 128, B_ * C_), dim3(256), 0, stream>>>(z, zbt);

    const size_t base_b = ztf * 2 + (size_t)B_ * CK_ * M_ * 2;   // 6 MiB
    if (ws_size >= base_b + (size_t)8 * ztf * 2) {
        zt_mfma_kernel<8><<<dim3(8, N_ / 128, B_), dim3(512), 0, stream>>>(xz, x, zbt, ls, ztp);
        zt_reduce_copy_kernel<8><<<dim3(1028), dim3(256), 0, stream>>>(ztp, ztb, xz, out);
    } else if (ws_size >= base_b + (size_t)4 * ztf * 2) {
        zt_mfma_kernel<4><<<dim3(4, N_ / 128, B_), dim3(512), 0, stream>>>(xz, x, zbt, ls, ztp);
        zt_reduce_copy_kernel<4><<<dim3(1028), dim3(256), 0, stream>>>(ztp, ztb, xz, out);
    } else {
        zt_mfma_kernel<2><<<dim3(2, N_ / 128, B_), dim3(512), 0, stream>>>(xz, x, zbt, ls, ztp);
        zt_reduce_copy_kernel<2><<<dim3(1028), dim3(256), 0, stream>>>(ztp, ztb, xz, out);
    }

    out_mfma_kernel<<<dim3(N_ / TB, N_ / TB, B_ * C_), dim3(256), 0, stream>>>(ztb, out + M_);
}